// Round 2
// baseline (260.035 us; speedup 1.0000x reference)
//
#include <hip/hip_runtime.h>
#include <hip/hip_bf16.h>
#include <math.h>

typedef float  f32x4 __attribute__((ext_vector_type(4)));
typedef short  s16x8 __attribute__((ext_vector_type(8)));
typedef unsigned short u16x4 __attribute__((ext_vector_type(4)));

__device__ inline unsigned short bfc(float f){
  __hip_bfloat16 h = __float2bfloat16(f);
  unsigned short u; __builtin_memcpy(&u, &h, 2); return u;
}

// ---- weight cvt (4 weights) + mask->float addend (log2 domain), one dispatch ----
__global__ __launch_bounds__(256) void wcvt(const float* __restrict__ w0, const float* __restrict__ w1,
                                            const float* __restrict__ w2, const float* __restrict__ w3,
                                            const unsigned char* __restrict__ mask,
                                            unsigned short* __restrict__ wb, float* __restrict__ mf){
  int y = blockIdx.y;
  int i = (blockIdx.x * 256 + threadIdx.x) * 4;
  if (y < 4){
    const float* src = y==0 ? w0 : y==1 ? w1 : y==2 ? w2 : w3;
    unsigned short* dst = wb + y * 262144;
    f32x4 v = *(const f32x4*)(src + i);
    u16x4 o = { bfc(v.x), bfc(v.y), bfc(v.z), bfc(v.w) };
    *(u16x4*)(dst + i) = o;
  } else {
    if (i < 4096){
#pragma unroll
      for (int j = 0; j < 4; ++j)
        mf[i+j] = mask[i+j] ? -1.442695e9f : 0.0f;
    }
  }
}

// ---- 3 projections fused in one dispatch (z selects), fp32 A converted inline ----
__global__ __launch_bounds__(256) void proj_gemm(const float* __restrict__ qin, const float* __restrict__ kin,
    const float* __restrict__ vin, const unsigned short* __restrict__ wb,
    const float* __restrict__ bq, const float* __restrict__ bk, const float* __restrict__ bv,
    unsigned short* __restrict__ pout){
  int z = blockIdx.z;
  const float* A = z==0 ? qin : (z==1 ? kin : vin);
  const unsigned short* W = wb + z * 262144;
  const float* bias = z==0 ? bq : (z==1 ? bk : bv);
  unsigned short* out = pout + (size_t)z * 2097152;

  int w = threadIdx.x >> 6, lane = threadIdx.x & 63;
  int lr = lane & 15, lg = lane >> 4;
  int arow = blockIdx.x * 64 + w * 16 + lr;
  int wrow0 = blockIdx.y * 64;
  f32x4 acc[4] = {}, acc2[4] = {};
  const float* Ap = A + (size_t)arow * 512 + lg * 8;
#pragma unroll 4
  for (int ks = 0; ks < 256; ks += 32){
    f32x4 a0 = *(const f32x4*)(Ap + ks);
    f32x4 a1 = *(const f32x4*)(Ap + ks + 4);
    f32x4 c0 = *(const f32x4*)(Ap + 256 + ks);
    f32x4 c1 = *(const f32x4*)(Ap + 256 + ks + 4);
    s16x8 af0 = { (short)bfc(a0.x),(short)bfc(a0.y),(short)bfc(a0.z),(short)bfc(a0.w),
                  (short)bfc(a1.x),(short)bfc(a1.y),(short)bfc(a1.z),(short)bfc(a1.w) };
    s16x8 af1 = { (short)bfc(c0.x),(short)bfc(c0.y),(short)bfc(c0.z),(short)bfc(c0.w),
                  (short)bfc(c1.x),(short)bfc(c1.y),(short)bfc(c1.z),(short)bfc(c1.w) };
#pragma unroll
    for (int n = 0; n < 4; ++n){
      const unsigned short* wr = W + (size_t)(wrow0 + n*16 + lr) * 512 + ks + lg * 8;
      s16x8 bf0 = *(const s16x8*)wr;
      s16x8 bf1 = *(const s16x8*)(wr + 256);
      acc[n]  = __builtin_amdgcn_mfma_f32_16x16x32_bf16(af0, bf0, acc[n],  0, 0, 0);
      acc2[n] = __builtin_amdgcn_mfma_f32_16x16x32_bf16(af1, bf1, acc2[n], 0, 0, 0);
    }
  }
  int orow = blockIdx.x * 64 + w * 16 + lg * 4;
#pragma unroll
  for (int n = 0; n < 4; ++n){
    int col = wrow0 + n * 16 + lr;
    float bv_ = bias[col];
#pragma unroll
    for (int r = 0; r < 4; ++r)
      out[(size_t)(orow + r) * 512 + col] = bfc(acc[n][r] + acc2[n][r] + bv_);
  }
}

// ---- Vt[bh][d=64][key=2048] = V_h[key][d] ----
__global__ __launch_bounds__(256) void vtrans(const unsigned short* __restrict__ Pv,
                                              unsigned short* __restrict__ Vt){
  int kt = blockIdx.x, bh = blockIdx.y;
  int b = bh >> 3, h = bh & 7;
  __shared__ unsigned short t[64][65];
  const unsigned short* src = Pv + (size_t)(b*2048 + h*256)*512 + kt*4096;
  for (int i = threadIdx.x; i < 4096; i += 256){ int r = i >> 6, c = i & 63; t[r][c] = src[i]; }
  __syncthreads();
  unsigned short* dst = Vt + (size_t)bh*131072 + kt*64;
  for (int i = threadIdx.x; i < 4096; i += 256){ int d = i >> 6, kk = i & 63; dst[(size_t)d*2048 + kk] = t[kk][d]; }
}

// ---- flash attention, swapped-QK^T orientation ----
// S^T = mfma(K,Q): C col=lane&15=q, row=(lane>>4)*4+r=key (within 16-tile).
// O^T = mfma(Vt,P^T): A=Vt rows (contiguous), B=P rows from LDS [q][key].
__global__ __launch_bounds__(256) void flash(const unsigned short* __restrict__ Pq,
                                             const unsigned short* __restrict__ Pk,
                                             const unsigned short* __restrict__ Vt,
                                             const float* __restrict__ mf,
                                             unsigned short* __restrict__ attnOut){
  int qt = blockIdx.x;          // 0..31
  int bh = blockIdx.y;          // 0..15
  int b = bh >> 3, h = bh & 7;
  int w = threadIdx.x >> 6, lane = threadIdx.x & 63;
  int lr = lane & 15, lg = lane >> 4;

  const unsigned short* Qh  = Pq + (size_t)(b*2048 + h*256)*512;  // [2048][64]
  const unsigned short* Kh  = Pk + (size_t)(b*2048 + h*256)*512;  // [2048][64]
  const unsigned short* Vth = Vt + (size_t)bh*131072;             // [64][2048]
  const float* mrow = mf + b*2048;

  __shared__ unsigned short plds[4][16][136];   // per-wave P[q=16][key=128] (+pad)

  int q = qt*64 + w*16 + lr;
  s16x8 qf0 = *(const s16x8*)(Qh + (size_t)q*64 + lg*8);
  s16x8 qf1 = *(const s16x8*)(Qh + (size_t)q*64 + 32 + lg*8);

  float m2 = -INFINITY, l = 0.f;
  f32x4 accT[4] = {};   // accT[nd][r] = O^T[d=nd*16+lg*4+r][q=lr]

  for (int kt = 0; kt < 2048; kt += 128){
    float s2[8][4];
    // --- S^T = K Q^T, scale*log2e + mask addend fused ---
#pragma unroll
    for (int n = 0; n < 8; ++n){
      const unsigned short* kr = Kh + (size_t)(kt + n*16 + lr)*64 + lg*8;
      s16x8 kf0 = *(const s16x8*)kr;
      s16x8 kf1 = *(const s16x8*)(kr + 32);
      f32x4 a = {};
      a = __builtin_amdgcn_mfma_f32_16x16x32_bf16(kf0, qf0, a, 0, 0, 0);
      a = __builtin_amdgcn_mfma_f32_16x16x32_bf16(kf1, qf1, a, 0, 0, 0);
      f32x4 mv = *(const f32x4*)(mrow + kt + n*16 + lg*4);
#pragma unroll
      for (int r = 0; r < 4; ++r)
        s2[n][r] = __builtin_fmaf(a[r], 0.18033688f, mv[r]);   // log2e/8
    }
    // --- rowmax: within-lane tree + 2 shfls ---
    float t[8];
#pragma unroll
    for (int n = 0; n < 8; ++n)
      t[n] = fmaxf(fmaxf(s2[n][0], s2[n][1]), fmaxf(s2[n][2], s2[n][3]));
    float rm = fmaxf(fmaxf(fmaxf(t[0],t[1]), fmaxf(t[2],t[3])),
                     fmaxf(fmaxf(t[4],t[5]), fmaxf(t[6],t[7])));
    rm = fmaxf(rm, __shfl_xor(rm, 16));
    rm = fmaxf(rm, __shfl_xor(rm, 32));
    // --- defer-max: rescale only when max grew by > 8/ln2 ---
    if (!__all(rm <= m2 + 11.54f)){
      float mn = fmaxf(m2, rm);
      float al = exp2f(m2 - mn);
      l *= al;
#pragma unroll
      for (int nd = 0; nd < 4; ++nd)
#pragma unroll
        for (int r = 0; r < 4; ++r) accT[nd][r] *= al;
      m2 = mn;
    }
    // --- P = exp2(S2 - m2), per-lane partial l, vector pack to LDS ---
#pragma unroll
    for (int n = 0; n < 8; ++n){
      float p0 = exp2f(s2[n][0] - m2);
      float p1 = exp2f(s2[n][1] - m2);
      float p2 = exp2f(s2[n][2] - m2);
      float p3 = exp2f(s2[n][3] - m2);
      l += (p0 + p1) + (p2 + p3);
      u16x4 pk = { bfc(p0), bfc(p1), bfc(p2), bfc(p3) };
      *(u16x4*)&plds[w][lr][n*16 + lg*4] = pk;   // 4 consecutive keys for q=lr
    }
    // --- O^T += V^T P^T ---
#pragma unroll
    for (int kh = 0; kh < 4; ++kh){
      s16x8 pf = *(const s16x8*)&plds[w][lr][kh*32 + lg*8];
#pragma unroll
      for (int nd = 0; nd < 4; ++nd){
        s16x8 vf = *(const s16x8*)(Vth + (size_t)(nd*16 + lr)*2048 + kt + kh*32 + lg*8);
        accT[nd] = __builtin_amdgcn_mfma_f32_16x16x32_bf16(vf, pf, accT[nd], 0, 0, 0);
      }
    }
  }
  // --- reduce l across lane-groups (once), normalize, write ---
  float lt = l + __shfl_xor(l, 16);
  lt += __shfl_xor(lt, 32);
  float inv = (lt > 0.f) ? 1.f / lt : 0.f;
  unsigned short* orow = attnOut + (size_t)(b*2048 + q)*512 + h*64;
#pragma unroll
  for (int nd = 0; nd < 4; ++nd){
    u16x4 ov = { bfc(accT[nd][0]*inv), bfc(accT[nd][1]*inv),
                 bfc(accT[nd][2]*inv), bfc(accT[nd][3]*inv) };
    *(u16x4*)(orow + nd*16 + lg*4) = ov;   // d = nd*16+lg*4+r, consecutive
  }
}

// ---- output projection: C = A[4096,512](bf16) @ Wm^T + bm -> fp32 ----
__global__ __launch_bounds__(256) void gemm_out(const unsigned short* __restrict__ A,
                                                const unsigned short* __restrict__ W,
                                                const float* __restrict__ bias,
                                                float* __restrict__ out){
  int w = threadIdx.x >> 6, lane = threadIdx.x & 63;
  int lr = lane & 15, lg = lane >> 4;
  int arow = blockIdx.x * 64 + w * 16 + lr;
  int wrow0 = blockIdx.y * 64;
  f32x4 acc[4] = {}, acc2[4] = {};
  const unsigned short* Ap = A + (size_t)arow * 512 + lg * 8;
#pragma unroll 4
  for (int ks = 0; ks < 256; ks += 32){
    s16x8 af0 = *(const s16x8*)(Ap + ks);
    s16x8 af1 = *(const s16x8*)(Ap + 256 + ks);
#pragma unroll
    for (int n = 0; n < 4; ++n){
      const unsigned short* wr = W + (size_t)(wrow0 + n*16 + lr) * 512 + ks + lg * 8;
      s16x8 bf0 = *(const s16x8*)wr;
      s16x8 bf1 = *(const s16x8*)(wr + 256);
      acc[n]  = __builtin_amdgcn_mfma_f32_16x16x32_bf16(af0, bf0, acc[n],  0, 0, 0);
      acc2[n] = __builtin_amdgcn_mfma_f32_16x16x32_bf16(af1, bf1, acc2[n], 0, 0, 0);
    }
  }
  int orow = blockIdx.x * 64 + w * 16 + lg * 4;
#pragma unroll
  for (int n = 0; n < 4; ++n){
    int col = wrow0 + n * 16 + lr;
    float bv_ = bias[col];
#pragma unroll
    for (int r = 0; r < 4; ++r)
      out[(size_t)(orow + r) * 512 + col] = acc[n][r] + acc2[n][r] + bv_;
  }
}

extern "C" void kernel_launch(void* const* d_in, const int* in_sizes, int n_in,
                              void* d_out, int out_size, void* d_ws, size_t ws_size,
                              hipStream_t stream) {
  const float* q  = (const float*)d_in[0];
  const float* k  = (const float*)d_in[1];
  const float* v  = (const float*)d_in[2];
  const unsigned char* mask = (const unsigned char*)d_in[3];
  const float* Wq = (const float*)d_in[4];
  const float* Wk = (const float*)d_in[5];
  const float* Wv = (const float*)d_in[6];
  const float* Wm = (const float*)d_in[7];
  const float* bq = (const float*)d_in[8];
  const float* bk = (const float*)d_in[9];
  const float* bv = (const float*)d_in[10];
  const float* bm = (const float*)d_in[11];

  unsigned short* ws = (unsigned short*)d_ws;
  // layout (in 2-byte units):
  unsigned short* WB = ws;                         // 4 x 262144 bf16 weights
  float*          MF = (float*)(ws + 1048576);     // 4096 floats (mask addend, log2 dom)
  unsigned short* PQ = ws + 1056768;               // 3 x 2097152 (Pq, Pk, Pv)
  unsigned short* VT = ws + 7348224;               // 2097152
  unsigned short* AO = ws + 9445376;               // 2097152

  wcvt<<<dim3(256, 5), 256, 0, stream>>>(Wq, Wk, Wv, Wm, mask, WB, MF);
  proj_gemm<<<dim3(64, 8, 3), 256, 0, stream>>>(q, k, v, WB, bq, bk, bv, PQ);
  vtrans<<<dim3(32, 16), 256, 0, stream>>>(PQ + 2*2097152, VT);
  flash<<<dim3(32, 16), 256, 0, stream>>>(PQ, PQ + 2097152, VT, MF, AO);
  gemm_out<<<dim3(64, 8), 256, 0, stream>>>(AO, WB + 3*262144, bm, (float*)d_out);
}

// Round 3
// 218.684 us; speedup vs baseline: 1.1891x; 1.1891x over previous
//
#include <hip/hip_runtime.h>
#include <hip/hip_bf16.h>
#include <math.h>

typedef float  f32x4 __attribute__((ext_vector_type(4)));
typedef short  s16x8 __attribute__((ext_vector_type(8)));
typedef unsigned short u16x4 __attribute__((ext_vector_type(4)));

__device__ inline unsigned short bfc(float f){
  __hip_bfloat16 h = __float2bfloat16(f);
  unsigned short u; __builtin_memcpy(&u, &h, 2); return u;
}

// ---- q,k,v fp32 -> bf16, one dispatch ----
__global__ __launch_bounds__(256) void cvt_qkv(const float* __restrict__ q, const float* __restrict__ k,
                                               const float* __restrict__ v, unsigned short* __restrict__ dst){
  int y = blockIdx.y;
  const float* src = y==0 ? q : (y==1 ? k : v);
  unsigned short* d = dst + (size_t)y * 2097152;
  int i = (blockIdx.x * 256 + threadIdx.x) * 4;
  f32x4 vv = *(const f32x4*)(src + i);
  u16x4 o = { bfc(vv.x), bfc(vv.y), bfc(vv.z), bfc(vv.w) };
  *(u16x4*)(d + i) = o;
}

// ---- weight cvt (4 weights) + mask->float addend (log2 domain) ----
__global__ __launch_bounds__(256) void wcvt(const float* __restrict__ w0, const float* __restrict__ w1,
                                            const float* __restrict__ w2, const float* __restrict__ w3,
                                            const unsigned char* __restrict__ mask,
                                            unsigned short* __restrict__ wb, float* __restrict__ mf){
  int y = blockIdx.y;
  int i = (blockIdx.x * 256 + threadIdx.x) * 4;
  if (y < 4){
    const float* src = y==0 ? w0 : y==1 ? w1 : y==2 ? w2 : w3;
    unsigned short* dst = wb + y * 262144;
    f32x4 v = *(const f32x4*)(src + i);
    u16x4 o = { bfc(v.x), bfc(v.y), bfc(v.z), bfc(v.w) };
    *(u16x4*)(dst + i) = o;
  } else if (i < 4096){
#pragma unroll
    for (int j = 0; j < 4; ++j)
      mf[i+j] = mask[i+j] ? -1.442695e9f : 0.0f;
  }
}

// ---- 3 projections (bf16 A) fused via z ----
__global__ __launch_bounds__(256) void proj_gemm(const unsigned short* __restrict__ Ab,
    const unsigned short* __restrict__ wb,
    const float* __restrict__ bq, const float* __restrict__ bk, const float* __restrict__ bv,
    unsigned short* __restrict__ pout){
  int z = blockIdx.z;
  const unsigned short* A = Ab + (size_t)z * 2097152;
  const unsigned short* W = wb + z * 262144;
  const float* bias = z==0 ? bq : (z==1 ? bk : bv);
  unsigned short* out = pout + (size_t)z * 2097152;

  int w = threadIdx.x >> 6, lane = threadIdx.x & 63;
  int lr = lane & 15, lg = lane >> 4;
  int arow = blockIdx.x * 64 + w * 16 + lr;
  int wrow0 = blockIdx.y * 64;
  f32x4 acc[4] = {}, acc2[4] = {};
  const unsigned short* Ap = A + (size_t)arow * 512 + lg * 8;
#pragma unroll 4
  for (int ks = 0; ks < 256; ks += 32){
    s16x8 af0 = *(const s16x8*)(Ap + ks);
    s16x8 af1 = *(const s16x8*)(Ap + 256 + ks);
#pragma unroll
    for (int n = 0; n < 4; ++n){
      const unsigned short* wr = W + (size_t)(wrow0 + n*16 + lr) * 512 + ks + lg * 8;
      s16x8 bf0 = *(const s16x8*)wr;
      s16x8 bf1 = *(const s16x8*)(wr + 256);
      acc[n]  = __builtin_amdgcn_mfma_f32_16x16x32_bf16(af0, bf0, acc[n],  0, 0, 0);
      acc2[n] = __builtin_amdgcn_mfma_f32_16x16x32_bf16(af1, bf1, acc2[n], 0, 0, 0);
    }
  }
  int orow = blockIdx.x * 64 + w * 16 + lg * 4;
#pragma unroll
  for (int n = 0; n < 4; ++n){
    int col = wrow0 + n * 16 + lr;
    float bv_ = bias[col];
#pragma unroll
    for (int r = 0; r < 4; ++r)
      out[(size_t)(orow + r) * 512 + col] = bfc(acc[n][r] + acc2[n][r] + bv_);
  }
}

// ---- Vt[bh][d=64][key=2048] = V_h[key][d] ----
__global__ __launch_bounds__(256) void vtrans(const unsigned short* __restrict__ Pv,
                                              unsigned short* __restrict__ Vt){
  int kt = blockIdx.x, bh = blockIdx.y;
  int b = bh >> 3, h = bh & 7;
  __shared__ unsigned short t[64][65];
  const unsigned short* src = Pv + (size_t)(b*2048 + h*256)*512 + kt*4096;
  for (int i = threadIdx.x; i < 4096; i += 256){ int r = i >> 6, c = i & 63; t[r][c] = src[i]; }
  __syncthreads();
  unsigned short* dst = Vt + (size_t)bh*131072 + kt*64;
  for (int i = threadIdx.x; i < 4096; i += 256){ int d = i >> 6, kk = i & 63; dst[(size_t)d*2048 + kk] = t[kk][d]; }
}

// ---- flash attention: 8 waves = 4 q-subtiles x 2 KV halves, in-block merge ----
// S^T = mfma(K,Q): C col=lane&15=q, row=(lane>>4)*4+r=key.
// O^T = mfma(Vt,P^T): A=Vt rows (d), B=P rows [q][key] from LDS.
__global__ __launch_bounds__(512) void flash(const unsigned short* __restrict__ Pq,
                                             const unsigned short* __restrict__ Pk,
                                             const unsigned short* __restrict__ Vt,
                                             const float* __restrict__ mf,
                                             unsigned short* __restrict__ attnOut){
  int qt = blockIdx.x;          // 0..31
  int bh = blockIdx.y;          // 0..15
  int b = bh >> 3, h = bh & 7;
  int w = threadIdx.x >> 6;     // 0..7
  int wq = w & 3, wk = w >> 2;
  int lane = threadIdx.x & 63;
  int lr = lane & 15, lg = lane >> 4;

  const unsigned short* Qh  = Pq + (size_t)(b*2048 + h*256)*512;      // [2048][64]
  const unsigned short* Kh  = Pk + (size_t)(b*2048 + h*256)*512 + (size_t)wk*65536; // + 1024 keys
  const unsigned short* Vth = Vt + (size_t)bh*131072 + wk*1024;       // [64][2048], key offset
  const float* mrow = mf + b*2048 + wk*1024;

  // stride 152 shorts = 304B = 76 dwords (=12 mod 32): b128 reads hit each
  // 4-bank group with exactly 8 lanes (conflict-free min); b64 writes 4/slot.
  __shared__ unsigned short plds[8][16][152];
  __shared__ float mbuf[4][16];
  __shared__ float lbuf[4][16];
  __shared__ float obuf[4][64][17];

  int q = qt*64 + wq*16 + lr;
  s16x8 qf0 = *(const s16x8*)(Qh + (size_t)q*64 + lg*8);
  s16x8 qf1 = *(const s16x8*)(Qh + (size_t)q*64 + 32 + lg*8);

  float m2 = -INFINITY, l = 0.f;
  f32x4 accT[4] = {};   // accT[nd][r] = O^T[d=nd*16+lg*4+r][q=lr], this half

  for (int kt = 0; kt < 1024; kt += 64){
    float s2[4][4];
    // --- S^T = K Q^T (scale*log2e, mask addend fused) ---
    __builtin_amdgcn_s_setprio(1);
#pragma unroll
    for (int n = 0; n < 4; ++n){
      const unsigned short* kr = Kh + (size_t)(kt + n*16 + lr)*64 + lg*8;
      s16x8 kf0 = *(const s16x8*)kr;
      s16x8 kf1 = *(const s16x8*)(kr + 32);
      f32x4 a = {};
      a = __builtin_amdgcn_mfma_f32_16x16x32_bf16(kf0, qf0, a, 0, 0, 0);
      a = __builtin_amdgcn_mfma_f32_16x16x32_bf16(kf1, qf1, a, 0, 0, 0);
      f32x4 mv = *(const f32x4*)(mrow + kt + n*16 + lg*4);
#pragma unroll
      for (int r = 0; r < 4; ++r)
        s2[n][r] = __builtin_fmaf(a[r], 0.18033688f, mv[r]);   // log2e/8
    }
    __builtin_amdgcn_s_setprio(0);
    // --- rowmax: in-lane tree + 2 shfls ---
    float t0 = fmaxf(fmaxf(s2[0][0], s2[0][1]), fmaxf(s2[0][2], s2[0][3]));
    float t1 = fmaxf(fmaxf(s2[1][0], s2[1][1]), fmaxf(s2[1][2], s2[1][3]));
    float t2 = fmaxf(fmaxf(s2[2][0], s2[2][1]), fmaxf(s2[2][2], s2[2][3]));
    float t3 = fmaxf(fmaxf(s2[3][0], s2[3][1]), fmaxf(s2[3][2], s2[3][3]));
    float rm = fmaxf(fmaxf(t0, t1), fmaxf(t2, t3));
    rm = fmaxf(rm, __shfl_xor(rm, 16));
    rm = fmaxf(rm, __shfl_xor(rm, 32));
    // --- defer-max: rescale only when max grew > 8 nats ---
    if (!__all(rm <= m2 + 11.54f)){
      float mn = fmaxf(m2, rm);
      float al = __builtin_amdgcn_exp2f(m2 - mn);
      l *= al;
#pragma unroll
      for (int nd = 0; nd < 4; ++nd)
#pragma unroll
        for (int r = 0; r < 4; ++r) accT[nd][r] *= al;
      m2 = mn;
    }
    // --- P = exp2(S2 - m2), per-lane partial l, vector pack to LDS ---
#pragma unroll
    for (int n = 0; n < 4; ++n){
      float p0 = __builtin_amdgcn_exp2f(s2[n][0] - m2);
      float p1 = __builtin_amdgcn_exp2f(s2[n][1] - m2);
      float p2 = __builtin_amdgcn_exp2f(s2[n][2] - m2);
      float p3 = __builtin_amdgcn_exp2f(s2[n][3] - m2);
      l += (p0 + p1) + (p2 + p3);
      u16x4 pk = { bfc(p0), bfc(p1), bfc(p2), bfc(p3) };
      *(u16x4*)&plds[w][lr][n*16 + lg*4] = pk;
    }
    // --- O^T += V^T P^T ---
    __builtin_amdgcn_s_setprio(1);
#pragma unroll
    for (int kh = 0; kh < 2; ++kh){
      s16x8 pf = *(const s16x8*)&plds[w][lr][kh*32 + lg*8];
#pragma unroll
      for (int nd = 0; nd < 4; ++nd){
        s16x8 vf = *(const s16x8*)(Vth + (size_t)(nd*16 + lr)*2048 + kt + kh*32 + lg*8);
        accT[nd] = __builtin_amdgcn_mfma_f32_16x16x32_bf16(vf, pf, accT[nd], 0, 0, 0);
      }
    }
    __builtin_amdgcn_s_setprio(0);
  }
  // --- in-wave l reduce over lane groups ---
  float lt = l + __shfl_xor(l, 16);
  lt += __shfl_xor(lt, 32);
  // --- cross-half merge via LDS ---
  if (wk == 1){
    if (lg == 0){ mbuf[wq][lr] = m2; lbuf[wq][lr] = lt; }
#pragma unroll
    for (int nd = 0; nd < 4; ++nd)
#pragma unroll
      for (int r = 0; r < 4; ++r)
        obuf[wq][lane][nd*4 + r] = accT[nd][r];
  }
  __syncthreads();
  if (wk == 0){
    float m1 = mbuf[wq][lr];
    float l1 = lbuf[wq][lr];
    float mM = fmaxf(m2, m1);
    float a0 = __builtin_amdgcn_exp2f(m2 - mM);
    float a1 = __builtin_amdgcn_exp2f(m1 - mM);
    float inv = 1.f / (lt*a0 + l1*a1);
    unsigned short* orow = attnOut + (size_t)(b*2048 + q)*512 + h*64;
#pragma unroll
    for (int nd = 0; nd < 4; ++nd){
      u16x4 ov;
#pragma unroll
      for (int r = 0; r < 4; ++r){
        float v = (accT[nd][r]*a0 + obuf[wq][lane][nd*4 + r]*a1) * inv;
        ov[r] = bfc(v);
      }
      *(u16x4*)(orow + nd*16 + lg*4) = ov;
    }
  }
}

// ---- output projection: bf16 A @ Wm^T + bm -> fp32 ----
__global__ __launch_bounds__(256) void gemm_out(const unsigned short* __restrict__ A,
                                                const unsigned short* __restrict__ W,
                                                const float* __restrict__ bias,
                                                float* __restrict__ out){
  int w = threadIdx.x >> 6, lane = threadIdx.x & 63;
  int lr = lane & 15, lg = lane >> 4;
  int arow = blockIdx.x * 64 + w * 16 + lr;
  int wrow0 = blockIdx.y * 64;
  f32x4 acc[4] = {}, acc2[4] = {};
  const unsigned short* Ap = A + (size_t)arow * 512 + lg * 8;
#pragma unroll 4
  for (int ks = 0; ks < 256; ks += 32){
    s16x8 af0 = *(const s16x8*)(Ap + ks);
    s16x8 af1 = *(const s16x8*)(Ap + 256 + ks);
#pragma unroll
    for (int n = 0; n < 4; ++n){
      const unsigned short* wr = W + (size_t)(wrow0 + n*16 + lr) * 512 + ks + lg * 8;
      s16x8 bf0 = *(const s16x8*)wr;
      s16x8 bf1 = *(const s16x8*)(wr + 256);
      acc[n]  = __builtin_amdgcn_mfma_f32_16x16x32_bf16(af0, bf0, acc[n],  0, 0, 0);
      acc2[n] = __builtin_amdgcn_mfma_f32_16x16x32_bf16(af1, bf1, acc2[n], 0, 0, 0);
    }
  }
  int orow = blockIdx.x * 64 + w * 16 + lg * 4;
#pragma unroll
  for (int n = 0; n < 4; ++n){
    int col = wrow0 + n * 16 + lr;
    float bv_ = bias[col];
#pragma unroll
    for (int r = 0; r < 4; ++r)
      out[(size_t)(orow + r) * 512 + col] = acc[n][r] + acc2[n][r] + bv_;
  }
}

extern "C" void kernel_launch(void* const* d_in, const int* in_sizes, int n_in,
                              void* d_out, int out_size, void* d_ws, size_t ws_size,
                              hipStream_t stream) {
  const float* q  = (const float*)d_in[0];
  const float* k  = (const float*)d_in[1];
  const float* v  = (const float*)d_in[2];
  const unsigned char* mask = (const unsigned char*)d_in[3];
  const float* Wq = (const float*)d_in[4];
  const float* Wk = (const float*)d_in[5];
  const float* Wv = (const float*)d_in[6];
  const float* Wm = (const float*)d_in[7];
  const float* bq = (const float*)d_in[8];
  const float* bk = (const float*)d_in[9];
  const float* bv = (const float*)d_in[10];
  const float* bm = (const float*)d_in[11];

  unsigned short* ws = (unsigned short*)d_ws;
  // layout (2-byte units):
  unsigned short* WB   = ws;                       // 4 x 262144
  float*          MF   = (float*)(ws + 1048576);   // 4096 floats
  unsigned short* QKVB = ws + 1056768;             // 3 x 2097152 (bf16 q,k,v)
  unsigned short* PQ   = ws + 7348224;             // 3 x 2097152 (Pq, Pk, Pv)
  unsigned short* VT   = ws + 13639680;            // 2097152
  unsigned short* AO   = ws + 15736832;            // 2097152

  cvt_qkv<<<dim3(2048, 3), 256, 0, stream>>>(q, k, v, QKVB);
  wcvt<<<dim3(256, 5), 256, 0, stream>>>(Wq, Wk, Wv, Wm, mask, WB, MF);
  proj_gemm<<<dim3(64, 8, 3), 256, 0, stream>>>(QKVB, WB, bq, bk, bv, PQ);
  vtrans<<<dim3(32, 16), 256, 0, stream>>>(PQ + 2*2097152, VT);
  flash<<<dim3(32, 16), 512, 0, stream>>>(PQ, PQ + 2097152, VT, MF, AO);
  gemm_out<<<dim3(64, 8), 256, 0, stream>>>(AO, WB + 3*262144, bm, (float*)d_out);
}